// Round 2
// baseline (621.744 us; speedup 1.0000x reference)
//
#include <hip/hip_runtime.h>

// B=262144, C=6, P=64. Pure streaming elementwise:
//   out = heaviside(beta[c]*mem + (x*W + b) - heaviside(mem-thr)*thr - thr)
// Numerics: __f{mul,add,sub}_rn forbid FMA contraction -> bit-identical to the
// numpy reference at the heaviside boundaries (R0: absmax 0.0 -- keep these).
//
// R1: 4x grid-stride unroll (4 independent mem loads in flight per thread) +
// nontemporal load/store on the mem/out streams (no reuse; don't pollute L2).

#define BB 262144
#define CC 6
#define PP 64
#define TOTAL4 ((BB * CC * PP) / 4)      // 25,165,824 float4s
#define UNROLL 4
#define NTHREADS (TOTAL4 / UNROLL)       // 6,291,456 threads

typedef float v4f __attribute__((ext_vector_type(4)));

__device__ __constant__ float BETA_C[6] = {0.9f, 0.85f, 0.9f, 0.85f, 0.9f, 0.85f};
__device__ __constant__ float THR_C[6]  = {1.0f, 1.0f, 1.0f, 1.0f, 1.0f, 1.0f};

__device__ __forceinline__ float spike_elem(float mv, float xv, float wv, float bv,
                                            float beta, float thr) {
    float cur   = __fadd_rn(__fmul_rn(xv, wv), bv);
    float rterm = (mv > thr) ? thr : 0.0f;                     // reset * thr
    float mn    = __fsub_rn(__fadd_rn(__fmul_rn(beta, mv), cur), rterm);
    return (mn > thr) ? 1.0f : 0.0f;
}

__global__ __launch_bounds__(256) void snn_encoder_kernel(
    const float* __restrict__ x,    // (B, C)
    const float* __restrict__ W,    // (C, P)
    const float* __restrict__ bias, // (C, P)
    const float* __restrict__ mem,  // (B, C, P)
    float* __restrict__ out)        // (B, C*P)
{
    const int t = blockIdx.x * blockDim.x + threadIdx.x;   // < NTHREADS

    v4f   mv[UNROLL], wv[UNROLL], bv[UNROLL];
    float xv[UNROLL], beta[UNROLL], thr[UNROLL];
    int   j[UNROLL];

    // Phase 1: issue all loads (4 independent HBM float4 loads in flight).
#pragma unroll
    for (int u = 0; u < UNROLL; ++u) {
        const int idx = t + u * NTHREADS;     // coalesced within each u
        j[u] = idx << 2;                      // flat element index
        const int r = j[u] >> 6;              // row = b*C + c  (== x index)
        const int p = j[u] & 63;
        const int c = r % 6;

        mv[u] = __builtin_nontemporal_load((const v4f*)(mem + j[u]));
        xv[u] = x[r];
        wv[u] = *(const v4f*)(W    + c * PP + p);
        bv[u] = *(const v4f*)(bias + c * PP + p);
        beta[u] = BETA_C[c];
        thr[u]  = THR_C[c];
    }

    // Phase 2: compute + streaming store.
#pragma unroll
    for (int u = 0; u < UNROLL; ++u) {
        v4f o;
        o.x = spike_elem(mv[u].x, xv[u], wv[u].x, bv[u].x, beta[u], thr[u]);
        o.y = spike_elem(mv[u].y, xv[u], wv[u].y, bv[u].y, beta[u], thr[u]);
        o.z = spike_elem(mv[u].z, xv[u], wv[u].z, bv[u].z, beta[u], thr[u]);
        o.w = spike_elem(mv[u].w, xv[u], wv[u].w, bv[u].w, beta[u], thr[u]);
        __builtin_nontemporal_store(o, (v4f*)(out + j[u]));
    }
}

extern "C" void kernel_launch(void* const* d_in, const int* in_sizes, int n_in,
                              void* d_out, int out_size, void* d_ws, size_t ws_size,
                              hipStream_t stream) {
    const float* x    = (const float*)d_in[0];  // (B, C)
    const float* W    = (const float*)d_in[1];  // (C, P)
    const float* bias = (const float*)d_in[2];  // (C, P)
    const float* mem  = (const float*)d_in[3];  // (B, C, P)
    float* out = (float*)d_out;                 // (B, C*P)

    const int block = 256;
    const int grid  = NTHREADS / block;         // 24,576 blocks
    snn_encoder_kernel<<<grid, block, 0, stream>>>(x, W, bias, mem, out);
}